// Round 1
// baseline (2136.431 us; speedup 1.0000x reference)
//
#include <hip/hip_runtime.h>
#include <hip/hip_bf16.h>
#include <math.h>

#define BB 16
#define NN 8192
#define CC 128
#define KK 128
#define LL 4

using bf16 = __hip_bfloat16;

__device__ __forceinline__ float bf2f(unsigned short u){ return __uint_as_float(((unsigned int)u) << 16); }

__device__ __forceinline__ float4 ld4f(const float* __restrict__ p){ return *(const float4*)p; }
__device__ __forceinline__ float4 ld4f(const bf16* __restrict__ p){
  ushort4 u = *(const ushort4*)p;
  return make_float4(bf2f(u.x), bf2f(u.y), bf2f(u.z), bf2f(u.w));
}
__device__ __forceinline__ void st1(float* p, float v){ *p = v; }
__device__ __forceinline__ void st1(bf16* p, float v){ *p = __float2bfloat16(v); }

__device__ __forceinline__ float gelu_f(float v){ return 0.5f*v*(1.0f + erff(v*0.70710678f)); }

// ---------------------------------------------------------------- bases
// bc[b,k,x] = cos(g0*m0+g1*m1)*mask ; bs likewise with sin. Also m, s=w*N.
template<typename TB>
__global__ __launch_bounds__(256) void bases_kernel(
    const float* __restrict__ X, const float* __restrict__ modes,
    TB* __restrict__ bc, TB* __restrict__ bs,
    float* __restrict__ mA, float* __restrict__ sA)
{
  const int b = blockIdx.x;
  const int x = blockIdx.y*256 + threadIdx.x;
  const float* xp = X + ((size_t)b*NN + x)*7;
  const float g0 = xp[3], g1 = xp[4], wv = xp[5], mv = xp[6];
  mA[b*NN + x] = mv;
  sA[b*NN + x] = wv * (float)NN;
  const size_t base = (size_t)b*KK*NN + x;
  #pragma unroll 4
  for (int k = 0; k < KK; ++k){
    const float t = g0*modes[2*k] + g1*modes[2*k+1];
    float sn, cs;
    __sincosf(t, &sn, &cs);
    st1(&bc[base + (size_t)k*NN], cs*mv);
    st1(&bs[base + (size_t)k*NN], sn*mv);
  }
}

// ---------------------------------------------------------------- fc0
__global__ __launch_bounds__(256) void fc0_kernel(
    const float* __restrict__ X, const float* __restrict__ w,
    const float* __restrict__ bias, float* __restrict__ h)
{
  __shared__ float sw[3*CC];
  __shared__ float sb[CC];
  const int tid = threadIdx.x;
  if (tid < CC) sb[tid] = bias[tid];
  for (int i = tid; i < 3*CC; i += 256) sw[i] = w[i];
  __syncthreads();
  const int idx = blockIdx.x*256 + tid;        // = b*N + x
  const float* xp = X + (size_t)idx*7;
  const float x0 = xp[0], x1 = xp[1], x2 = xp[2];
  const int b = idx / NN, x = idx % NN;
  float* hp = h + (size_t)b*CC*NN + x;
  #pragma unroll 4
  for (int c = 0; c < CC; ++c){
    hp[(size_t)c*NN] = sb[c] + x0*sw[c] + x1*sw[CC+c] + x2*sw[2*CC+c];
  }
}

// ---------------------------------------------------------------- projection
// xc[b,i,k]=sum_x (h*s)*bc ; xs = -sum_x (h*s)*bs ; x0[b,i]=sum_x (h*s)*m
template<typename TB>
__global__ __launch_bounds__(256) void proj_kernel(
    const float* __restrict__ h, const TB* __restrict__ bc, const TB* __restrict__ bs,
    const float* __restrict__ sA, const float* __restrict__ mA,
    float* __restrict__ xc, float* __restrict__ xs, float* __restrict__ x0a)
{
  __shared__ float sh_hs[32*132];   // [x][i]
  __shared__ float sh_bc[32*68];    // [x][k(64)]
  __shared__ float sh_bs[32*68];
  __shared__ float sh_m[32];
  const int b  = blockIdx.x;
  const int kg = blockIdx.y;        // 0..1
  const int ch = blockIdx.z;        // 0..7
  const int tid = threadIdx.x;
  const int ti = tid >> 4;          // i-octet
  const int tk = tid & 15;          // k-quad
  const int k0 = kg*64;
  const bool do0 = (kg==0) && (tk==0);
  float accC[8][4], accS[8][4], acc0[8];
  #pragma unroll
  for (int a = 0; a < 8; ++a){ acc0[a]=0.f;
    #pragma unroll
    for (int q = 0; q < 4; ++q){ accC[a][q]=0.f; accS[a][q]=0.f; } }

  for (int xst = 0; xst < 1024; xst += 32){
    const int x0 = ch*1024 + xst;
    if (tid < 32) sh_m[tid] = mA[b*NN + x0 + tid];
    #pragma unroll 2
    for (int idx = tid; idx < 1024; idx += 256){
      const int i = idx >> 3, xq = idx & 7;
      const float4 v  = ld4f(h + (size_t)(b*CC + i)*NN + x0 + xq*4);
      const float4 sv = ld4f(sA + b*NN + x0 + xq*4);
      sh_hs[(xq*4+0)*132 + i] = v.x*sv.x;
      sh_hs[(xq*4+1)*132 + i] = v.y*sv.y;
      sh_hs[(xq*4+2)*132 + i] = v.z*sv.z;
      sh_hs[(xq*4+3)*132 + i] = v.w*sv.w;
    }
    #pragma unroll 2
    for (int idx = tid; idx < 512; idx += 256){
      const int k = idx >> 3, xq = idx & 7;
      const float4 vc = ld4f(bc + (size_t)(b*KK + k0 + k)*NN + x0 + xq*4);
      const float4 vs = ld4f(bs + (size_t)(b*KK + k0 + k)*NN + x0 + xq*4);
      sh_bc[(xq*4+0)*68 + k] = vc.x;  sh_bs[(xq*4+0)*68 + k] = vs.x;
      sh_bc[(xq*4+1)*68 + k] = vc.y;  sh_bs[(xq*4+1)*68 + k] = vs.y;
      sh_bc[(xq*4+2)*68 + k] = vc.z;  sh_bs[(xq*4+2)*68 + k] = vs.z;
      sh_bc[(xq*4+3)*68 + k] = vc.w;  sh_bs[(xq*4+3)*68 + k] = vs.w;
    }
    __syncthreads();
    #pragma unroll 4
    for (int x = 0; x < 32; ++x){
      const float4 a0 = *(const float4*)&sh_hs[x*132 + ti*8];
      const float4 a1 = *(const float4*)&sh_hs[x*132 + ti*8 + 4];
      const float4 cv = *(const float4*)&sh_bc[x*68 + tk*4];
      const float4 sv = *(const float4*)&sh_bs[x*68 + tk*4];
      const float av[8]  = {a0.x,a0.y,a0.z,a0.w,a1.x,a1.y,a1.z,a1.w};
      const float cva[4] = {cv.x,cv.y,cv.z,cv.w};
      const float sva[4] = {sv.x,sv.y,sv.z,sv.w};
      #pragma unroll
      for (int a = 0; a < 8; ++a){
        #pragma unroll
        for (int q = 0; q < 4; ++q){
          accC[a][q] += av[a]*cva[q];
          accS[a][q] += av[a]*sva[q];
        }
      }
      if (do0){
        const float mm = sh_m[x];
        #pragma unroll
        for (int a = 0; a < 8; ++a) acc0[a] += av[a]*mm;
      }
    }
    __syncthreads();
  }
  #pragma unroll
  for (int a = 0; a < 8; ++a){
    const int i = ti*8 + a;
    #pragma unroll
    for (int q = 0; q < 4; ++q){
      const int k = k0 + tk*4 + q;
      atomicAdd(&xc[(size_t)(b*CC + i)*KK + k],  accC[a][q]);
      atomicAdd(&xs[(size_t)(b*CC + i)*KK + k], -accS[a][q]);
    }
    if (do0) atomicAdd(&x0a[b*CC + i], acc0[a]);
  }
}

// ---------------------------------------------------------------- mix (f_c, f_s)
__global__ __launch_bounds__(128) void mix_kernel(
    const float* __restrict__ xc, const float* __restrict__ xs,
    const float* __restrict__ wcl, const float* __restrict__ wsl,
    float* __restrict__ fcb, float* __restrict__ fsb)
{
  const int b = blockIdx.x, og = blockIdx.y;   // og 0..15
  const int k = threadIdx.x;                   // 0..127
  const int o0 = og*8;
  float accC[8], accS[8];
  #pragma unroll
  for (int oo = 0; oo < 8; ++oo){ accC[oo]=0.f; accS[oo]=0.f; }
  for (int i = 0; i < CC; ++i){
    const float xcv = xc[(size_t)(b*CC+i)*KK + k];
    const float xsv = xs[(size_t)(b*CC+i)*KK + k];
    const float* wcp = wcl + ((size_t)i*CC + o0)*KK + k;
    const float* wsp = wsl + ((size_t)i*CC + o0)*KK + k;
    #pragma unroll
    for (int oo = 0; oo < 8; ++oo){
      const float a = wcp[(size_t)oo*KK];
      const float c = wsp[(size_t)oo*KK];
      accC[oo] += xcv*a - xsv*c;
      accS[oo] += xsv*a + xcv*c;
    }
  }
  const float inv = 1.0f/(float)NN;
  #pragma unroll
  for (int oo = 0; oo < 8; ++oo){
    fcb[(size_t)(b*CC + o0 + oo)*KK + k] = accC[oo]*inv;
    fsb[(size_t)(b*CC + o0 + oo)*KK + k] = accS[oo]*inv;
  }
}

__global__ __launch_bounds__(128) void f0_kernel(
    const float* __restrict__ x0a, const float* __restrict__ w0l, float* __restrict__ f0b)
{
  const int b = blockIdx.x, o = threadIdx.x;
  float acc = 0.f;
  for (int i = 0; i < CC; ++i) acc += x0a[b*CC+i] * w0l[i*CC + o];
  f0b[b*CC+o] = acc * (1.0f/(float)NN);
}

// ---------------------------------------------------------------- spectral reconstruction -> h2
template<typename TB>
__global__ __launch_bounds__(256) void recon_kernel(
    const TB* __restrict__ bc, const TB* __restrict__ bs,
    const float* __restrict__ fcb, const float* __restrict__ fsb,
    const float* __restrict__ f0b, const float* __restrict__ mA,
    float* __restrict__ h2)
{
  __shared__ float sh_fc[32*132];  // [k][o]
  __shared__ float sh_fs[32*132];
  __shared__ float sh_bc[32*132];  // [k][x]
  __shared__ float sh_bs[32*132];
  const int b = blockIdx.x;
  const int x0 = blockIdx.y*128;
  const int tid = threadIdx.x;
  const int tx = tid & 15;   // x-octet
  const int ty = tid >> 4;   // o-octet
  float acc[8][8];
  #pragma unroll
  for (int a = 0; a < 8; ++a)
    #pragma unroll
    for (int q = 0; q < 8; ++q) acc[a][q] = 0.f;

  for (int k0 = 0; k0 < KK; k0 += 32){
    #pragma unroll 2
    for (int idx = tid; idx < 1024; idx += 256){
      const int o = idx >> 3, kq = idx & 7;
      const float4 vc = ld4f(fcb + (size_t)(b*CC+o)*KK + k0 + kq*4);
      const float4 vs = ld4f(fsb + (size_t)(b*CC+o)*KK + k0 + kq*4);
      sh_fc[(kq*4+0)*132 + o] = vc.x;  sh_fs[(kq*4+0)*132 + o] = vs.x;
      sh_fc[(kq*4+1)*132 + o] = vc.y;  sh_fs[(kq*4+1)*132 + o] = vs.y;
      sh_fc[(kq*4+2)*132 + o] = vc.z;  sh_fs[(kq*4+2)*132 + o] = vs.z;
      sh_fc[(kq*4+3)*132 + o] = vc.w;  sh_fs[(kq*4+3)*132 + o] = vs.w;
    }
    #pragma unroll 2
    for (int idx = tid; idx < 1024; idx += 256){
      const int kk = idx >> 5, xq = idx & 31;
      const float4 vc = ld4f(bc + (size_t)(b*KK + k0 + kk)*NN + x0 + xq*4);
      const float4 vs = ld4f(bs + (size_t)(b*KK + k0 + kk)*NN + x0 + xq*4);
      *(float4*)&sh_bc[kk*132 + xq*4] = vc;
      *(float4*)&sh_bs[kk*132 + xq*4] = vs;
    }
    __syncthreads();
    #pragma unroll 4
    for (int kk = 0; kk < 32; ++kk){
      const float4 c0 = *(const float4*)&sh_fc[kk*132 + ty*8];
      const float4 c1 = *(const float4*)&sh_fc[kk*132 + ty*8 + 4];
      const float4 s0 = *(const float4*)&sh_fs[kk*132 + ty*8];
      const float4 s1 = *(const float4*)&sh_fs[kk*132 + ty*8 + 4];
      const float4 p0 = *(const float4*)&sh_bc[kk*132 + tx*8];
      const float4 p1 = *(const float4*)&sh_bc[kk*132 + tx*8 + 4];
      const float4 q0 = *(const float4*)&sh_bs[kk*132 + tx*8];
      const float4 q1 = *(const float4*)&sh_bs[kk*132 + tx*8 + 4];
      const float fcv[8] = {c0.x,c0.y,c0.z,c0.w,c1.x,c1.y,c1.z,c1.w};
      const float fsv[8] = {s0.x,s0.y,s0.z,s0.w,s1.x,s1.y,s1.z,s1.w};
      const float bcv[8] = {p0.x,p0.y,p0.z,p0.w,p1.x,p1.y,p1.z,p1.w};
      const float bsv[8] = {q0.x,q0.y,q0.z,q0.w,q1.x,q1.y,q1.z,q1.w};
      #pragma unroll
      for (int a = 0; a < 8; ++a)
        #pragma unroll
        for (int q = 0; q < 8; ++q)
          acc[a][q] += fcv[a]*bcv[q] - fsv[a]*bsv[q];
    }
    __syncthreads();
  }
  const float4 m0 = ld4f(mA + b*NN + x0 + tx*8);
  const float4 m1 = ld4f(mA + b*NN + x0 + tx*8 + 4);
  const float mv[8] = {m0.x,m0.y,m0.z,m0.w,m1.x,m1.y,m1.z,m1.w};
  #pragma unroll
  for (int a = 0; a < 8; ++a){
    const int o = ty*8 + a;
    const float f0v = f0b[b*CC + o];
    float* hp = h2 + (size_t)(b*CC+o)*NN + x0 + tx*8;
    float4 r0, r1;
    r0.x = f0v*mv[0] + 2.0f*acc[a][0];  r0.y = f0v*mv[1] + 2.0f*acc[a][1];
    r0.z = f0v*mv[2] + 2.0f*acc[a][2];  r0.w = f0v*mv[3] + 2.0f*acc[a][3];
    r1.x = f0v*mv[4] + 2.0f*acc[a][4];  r1.y = f0v*mv[5] + 2.0f*acc[a][5];
    r1.z = f0v*mv[6] + 2.0f*acc[a][6];  r1.w = f0v*mv[7] + 2.0f*acc[a][7];
    *(float4*)&hp[0] = r0;
    *(float4*)&hp[4] = r1;
  }
}

// ---------------------------------------------------------------- conv + residual + gelu, in-place on h
__global__ __launch_bounds__(256) void conv_kernel(
    const float* __restrict__ cw, const float* __restrict__ cb,
    const float* __restrict__ h2, float* __restrict__ h, const int act)
{
  __shared__ float sh_h[CC*68];    // [i][x(64)]
  __shared__ float sh_w[32*132];   // [ii][o]
  const int b = blockIdx.x;
  const int x0 = blockIdx.y*64;
  const int tid = threadIdx.x;
  const int xg = tid & 15;   // x-quad
  const int og = tid >> 4;   // o-octet
  for (int idx = tid; idx < CC*16; idx += 256){
    const int i = idx >> 4, xq = idx & 15;
    *(float4*)&sh_h[i*68 + xq*4] = ld4f(h + (size_t)(b*CC+i)*NN + x0 + xq*4);
  }
  float acc[8][4];
  #pragma unroll
  for (int a = 0; a < 8; ++a)
    #pragma unroll
    for (int q = 0; q < 4; ++q) acc[a][q] = 0.f;

  for (int i0 = 0; i0 < CC; i0 += 32){
    #pragma unroll 2
    for (int idx = tid; idx < 1024; idx += 256){
      const int o = idx >> 3, iq = idx & 7;
      const float4 v = ld4f(cw + (size_t)o*CC + i0 + iq*4);
      sh_w[(iq*4+0)*132 + o] = v.x;
      sh_w[(iq*4+1)*132 + o] = v.y;
      sh_w[(iq*4+2)*132 + o] = v.z;
      sh_w[(iq*4+3)*132 + o] = v.w;
    }
    __syncthreads();
    #pragma unroll 4
    for (int ii = 0; ii < 32; ++ii){
      const float4 w0v = *(const float4*)&sh_w[ii*132 + og*8];
      const float4 w1v = *(const float4*)&sh_w[ii*132 + og*8 + 4];
      const float4 hv  = *(const float4*)&sh_h[(i0+ii)*68 + xg*4];
      const float wv[8] = {w0v.x,w0v.y,w0v.z,w0v.w,w1v.x,w1v.y,w1v.z,w1v.w};
      const float hvv[4] = {hv.x,hv.y,hv.z,hv.w};
      #pragma unroll
      for (int a = 0; a < 8; ++a)
        #pragma unroll
        for (int q = 0; q < 4; ++q)
          acc[a][q] += wv[a]*hvv[q];
    }
    __syncthreads();
  }
  #pragma unroll
  for (int a = 0; a < 8; ++a){
    const int o = og*8 + a;
    const float bias = cb[o];
    const float4 r = ld4f(h2 + (size_t)(b*CC+o)*NN + x0 + xg*4);
    float4 v;
    v.x = acc[a][0] + bias + r.x;
    v.y = acc[a][1] + bias + r.y;
    v.z = acc[a][2] + bias + r.z;
    v.w = acc[a][3] + bias + r.w;
    if (act){ v.x = gelu_f(v.x); v.y = gelu_f(v.y); v.z = gelu_f(v.z); v.w = gelu_f(v.w); }
    *(float4*)(h + (size_t)(b*CC+o)*NN + x0 + xg*4) = v;
  }
}

// ---------------------------------------------------------------- final MLP
__global__ __launch_bounds__(256) void final_kernel(
    const float* __restrict__ h, const float* __restrict__ w1,
    const float* __restrict__ b1, const float* __restrict__ w2,
    const float* __restrict__ b2, float* __restrict__ out)
{
  __shared__ float sh_h[CC*68];     // [c][x(64)]
  __shared__ float sh_w[CC*132];    // [c][f]
  __shared__ float sh_red[64*17];
  const int b = blockIdx.x;
  const int x0 = blockIdx.y*64;
  const int tid = threadIdx.x;
  const int xg = tid & 15;   // x-quad
  const int fg = tid >> 4;   // f-octet
  for (int idx = tid; idx < CC*16; idx += 256){
    const int c = idx >> 4, xq = idx & 15;
    *(float4*)&sh_h[c*68 + xq*4] = ld4f(h + (size_t)(b*CC+c)*NN + x0 + xq*4);
  }
  for (int idx = tid; idx < CC*32; idx += 256){
    const int c = idx >> 5, fq = idx & 31;
    *(float4*)&sh_w[c*132 + fq*4] = ld4f(w1 + (size_t)c*128 + fq*4);
  }
  __syncthreads();
  float acc[4][8];
  #pragma unroll
  for (int q = 0; q < 4; ++q)
    #pragma unroll
    for (int a = 0; a < 8; ++a) acc[q][a] = 0.f;
  #pragma unroll 4
  for (int c = 0; c < CC; ++c){
    const float4 hv = *(const float4*)&sh_h[c*68 + xg*4];
    const float4 wa = *(const float4*)&sh_w[c*132 + fg*8];
    const float4 wb = *(const float4*)&sh_w[c*132 + fg*8 + 4];
    const float hvv[4] = {hv.x,hv.y,hv.z,hv.w};
    const float wv[8] = {wa.x,wa.y,wa.z,wa.w,wb.x,wb.y,wb.z,wb.w};
    #pragma unroll
    for (int q = 0; q < 4; ++q)
      #pragma unroll
      for (int a = 0; a < 8; ++a)
        acc[q][a] += hvv[q]*wv[a];
  }
  float p[4] = {0.f, 0.f, 0.f, 0.f};
  #pragma unroll
  for (int a = 0; a < 8; ++a){
    const float bb = b1[fg*8 + a];
    const float w2v = w2[fg*8 + a];
    #pragma unroll
    for (int q = 0; q < 4; ++q){
      p[q] += gelu_f(acc[q][a] + bb) * w2v;
    }
  }
  #pragma unroll
  for (int q = 0; q < 4; ++q) sh_red[(xg*4+q)*17 + fg] = p[q];
  __syncthreads();
  if (tid < 64){
    float sum = b2[0];
    #pragma unroll
    for (int j = 0; j < 16; ++j) sum += sh_red[tid*17 + j];
    out[(size_t)b*NN + x0 + tid] = sum;
  }
}

// ---------------------------------------------------------------- host
template<typename TB>
static void run_pipeline(const float* X, const float* modes, const float* fc0w, const float* fc0b,
                         const float* wc, const float* wsm, const float* w0,
                         const float* convw, const float* convb,
                         const float* fc1w, const float* fc1b, const float* fc2w, const float* fc2b,
                         float* out, char* ws, hipStream_t stream)
{
  const size_t nBKN = (size_t)BB*KK*NN;
  const size_t nBCN = (size_t)BB*CC*NN;
  const size_t nBCK = (size_t)BB*CC*KK;
  const size_t nBC  = (size_t)BB*CC;
  const size_t nBN  = (size_t)BB*NN;
  TB* bc = (TB*)ws;
  TB* bs = bc + nBKN;
  float* f = (float*)(bs + nBKN);
  float* h   = f;  f += nBCN;
  float* h2  = f;  f += nBCN;
  float* xc  = f;  f += nBCK;
  float* xs  = f;  f += nBCK;
  float* x0a = f;  f += nBC;
  float* fcb = f;  f += nBCK;
  float* fsb = f;  f += nBCK;
  float* f0b = f;  f += nBC;
  float* mA  = f;  f += nBN;
  float* sA  = f;  f += nBN;

  bases_kernel<TB><<<dim3(BB, NN/256), 256, 0, stream>>>(X, modes, bc, bs, mA, sA);
  fc0_kernel<<<dim3((BB*NN)/256), 256, 0, stream>>>(X, fc0w, fc0b, h);
  for (int l = 0; l < LL; ++l){
    hipMemsetAsync(xc, 0, (2*nBCK + nBC)*sizeof(float), stream);
    proj_kernel<TB><<<dim3(BB, 2, 8), 256, 0, stream>>>(h, bc, bs, sA, mA, xc, xs, x0a);
    mix_kernel<<<dim3(BB, 16), 128, 0, stream>>>(xc, xs,
        wc + (size_t)l*CC*CC*KK, wsm + (size_t)l*CC*CC*KK, fcb, fsb);
    f0_kernel<<<dim3(BB), 128, 0, stream>>>(x0a, w0 + (size_t)l*CC*CC, f0b);
    recon_kernel<TB><<<dim3(BB, NN/128), 256, 0, stream>>>(bc, bs, fcb, fsb, f0b, mA, h2);
    conv_kernel<<<dim3(BB, NN/64), 256, 0, stream>>>(convw + (size_t)l*CC*CC, convb + (size_t)l*CC,
        h2, h, (l != LL-1) ? 1 : 0);
  }
  final_kernel<<<dim3(BB, NN/64), 256, 0, stream>>>(h, fc1w, fc1b, fc2w, fc2b, out);
}

extern "C" void kernel_launch(void* const* d_in, const int* in_sizes, int n_in,
                              void* d_out, int out_size, void* d_ws, size_t ws_size,
                              hipStream_t stream)
{
  const float* X     = (const float*)d_in[0];
  const float* modes = (const float*)d_in[1];
  const float* fc0w  = (const float*)d_in[2];
  const float* fc0b  = (const float*)d_in[3];
  const float* wc    = (const float*)d_in[4];
  const float* wsm   = (const float*)d_in[5];
  const float* w0    = (const float*)d_in[6];
  const float* convw = (const float*)d_in[7];
  const float* convb = (const float*)d_in[8];
  const float* fc1w  = (const float*)d_in[9];
  const float* fc1b  = (const float*)d_in[10];
  const float* fc2w  = (const float*)d_in[11];
  const float* fc2b  = (const float*)d_in[12];
  float* out = (float*)d_out;

  const size_t nBKN = (size_t)BB*KK*NN;
  const size_t nBCN = (size_t)BB*CC*NN;
  const size_t nBCK = (size_t)BB*CC*KK;
  const size_t nBC  = (size_t)BB*CC;
  const size_t nBN  = (size_t)BB*NN;
  const size_t small_bytes = (2*nBCN + 4*nBCK + 2*nBC + 2*nBN) * sizeof(float);
  const size_t need_f32 = small_bytes + 2*nBKN*sizeof(float);

  if (ws_size >= need_f32){
    run_pipeline<float>(X, modes, fc0w, fc0b, wc, wsm, w0, convw, convb,
                        fc1w, fc1b, fc2w, fc2b, out, (char*)d_ws, stream);
  } else {
    run_pipeline<bf16>(X, modes, fc0w, fc0b, wc, wsm, w0, convw, convb,
                       fc1w, fc1b, fc2w, fc2b, out, (char*)d_ws, stream);
  }
}

// Round 2
// 981.145 us; speedup vs baseline: 2.1775x; 2.1775x over previous
//
#include <hip/hip_runtime.h>
#include <math.h>

#define BB 16
#define NN 8192
#define CC 128
#define KK 128
#define LL 4

#define APX 40    // LDS row stride (elems) for [row][32] staging tiles (pad vs 32)
#define BPX 136   // LDS row stride (elems) for 128-wide tiles (16B-aligned rows)

typedef short bf16x8 __attribute__((ext_vector_type(8)));
typedef float f32x4 __attribute__((ext_vector_type(4)));

typedef unsigned short u16;
typedef unsigned int u32;

__device__ __forceinline__ float gelu_f(float v){ return 0.5f*v*(1.0f + erff(v*0.70710678118f)); }

__device__ __forceinline__ u16 f2bf(float f){
  u32 u = __float_as_uint(f);
  return (u16)((u + 0x7FFFu + ((u >> 16) & 1u)) >> 16);   // RNE
}
__device__ __forceinline__ float bf2f(u16 u){ return __uint_as_float(((u32)u) << 16); }

__device__ __forceinline__ u32 pk2(float a, float b){
  return (u32)f2bf(a) | ((u32)f2bf(b) << 16);
}

// ---------------------------------------------------------------- bases
// bc[b][k][x] = cos(g.modes_k)*mask (x-contig, for proj)
// bcT[b][x][k] = same, k-contig (for fused spectral)  ; likewise bs/bsT with sin
__global__ __launch_bounds__(256) void bases_kernel(
    const float* __restrict__ X, const float* __restrict__ modes,
    u16* __restrict__ bc, u16* __restrict__ bs,
    u16* __restrict__ bcT, u16* __restrict__ bsT,
    float* __restrict__ mA, float* __restrict__ sA)
{
  __shared__ float smodes[2*KK];
  __shared__ u16 shc[64*BPX];
  __shared__ u16 shs[64*BPX];
  const int b = blockIdx.x;
  const int x0 = blockIdx.y*64;
  const int t = threadIdx.x;
  smodes[t] = modes[t];          // 256 = 2*KK
  const int xl = t & 63;
  const int kq = t >> 6;         // 0..3
  const int x = x0 + xl;
  const float* xp = X + ((size_t)b*NN + x)*7;
  const float g0 = xp[3], g1 = xp[4], wv = xp[5], mv = xp[6];
  if (kq == 0){
    mA[b*NN + x] = mv;
    sA[b*NN + x] = wv * (float)NN;
  }
  __syncthreads();
  #pragma unroll 4
  for (int kk = 0; kk < 32; ++kk){
    const int k = kq*32 + kk;
    const float tt = g0*smodes[2*k] + g1*smodes[2*k+1];
    float sn, cs;
    __sincosf(tt, &sn, &cs);
    shc[xl*BPX + k] = f2bf(cs*mv);
    shs[xl*BPX + k] = f2bf(sn*mv);
  }
  __syncthreads();
  // coalesced write of [x][k] layout
  for (int idx = t; idx < 64*16; idx += 256){
    const int row = idx >> 4, c16 = (idx & 15)*8;
    const size_t dst = ((size_t)b*NN + x0 + row)*KK + c16;
    *(uint4*)&bcT[dst] = *(const uint4*)&shc[row*BPX + c16];
    *(uint4*)&bsT[dst] = *(const uint4*)&shs[row*BPX + c16];
  }
  // transposed write of [k][x] layout
  for (int idx = t; idx < 128*8; idx += 256){
    const int k = idx >> 3, x8 = (idx & 7)*8;
    uint4 vc, vs;
    vc.x = (u32)shc[(x8+0)*BPX+k] | ((u32)shc[(x8+1)*BPX+k] << 16);
    vc.y = (u32)shc[(x8+2)*BPX+k] | ((u32)shc[(x8+3)*BPX+k] << 16);
    vc.z = (u32)shc[(x8+4)*BPX+k] | ((u32)shc[(x8+5)*BPX+k] << 16);
    vc.w = (u32)shc[(x8+6)*BPX+k] | ((u32)shc[(x8+7)*BPX+k] << 16);
    vs.x = (u32)shs[(x8+0)*BPX+k] | ((u32)shs[(x8+1)*BPX+k] << 16);
    vs.y = (u32)shs[(x8+2)*BPX+k] | ((u32)shs[(x8+3)*BPX+k] << 16);
    vs.z = (u32)shs[(x8+4)*BPX+k] | ((u32)shs[(x8+5)*BPX+k] << 16);
    vs.w = (u32)shs[(x8+6)*BPX+k] | ((u32)shs[(x8+7)*BPX+k] << 16);
    const size_t dst = ((size_t)b*KK + k)*NN + x0 + x8;
    *(uint4*)&bc[dst] = vc;
    *(uint4*)&bs[dst] = vs;
  }
}

// ---------------------------------------------------------------- cvt (weights -> bf16)
__global__ __launch_bounds__(256) void cvt_kernel(
    const float* __restrict__ convw, const float* __restrict__ fc1w,
    u16* __restrict__ cwb, u16* __restrict__ w1T)
{
  const int t = threadIdx.x;
  for (int i = t; i < LL*CC*CC; i += 256) cwb[i] = f2bf(convw[i]);
  for (int i = t; i < CC*CC; i += 256){
    const int f = i >> 7, c = i & 127;
    w1T[i] = f2bf(fc1w[(size_t)c*CC + f]);   // w1T[f][c]
  }
}

// ---------------------------------------------------------------- fc0 -> hs, hT, x0[0]
__global__ __launch_bounds__(256) void fc0_kernel(
    const float* __restrict__ X, const float* __restrict__ w, const float* __restrict__ bias,
    const float* __restrict__ mA, const float* __restrict__ sA,
    u16* __restrict__ hs, u16* __restrict__ hT, float* __restrict__ x0out)
{
  __shared__ float sxin[3*128];
  __shared__ float sw[3*128];
  __shared__ float sb[128];
  __shared__ float sm[128], ss[128];
  __shared__ u16 sht[128*BPX];   // [x][c]
  const int b = blockIdx.x;
  const int x0 = blockIdx.y*128;
  const int t = threadIdx.x;
  if (t < 128){
    sb[t] = bias[t];
    sm[t] = mA[b*NN + x0 + t];
    ss[t] = sA[b*NN + x0 + t];
    #pragma unroll
    for (int j = 0; j < 3; ++j){
      sw[j*128 + t] = w[j*128 + t];
      sxin[j*128 + t] = X[((size_t)b*NN + x0 + t)*7 + j];
    }
  }
  __syncthreads();
  const int o = t >> 1;
  const int xh = (t & 1)*64;
  const float w0v = sw[o], w1v = sw[128+o], w2v = sw[256+o], bv = sb[o];
  float xacc = 0.f;
  for (int j = 0; j < 8; ++j){
    uint4 q;
    u32 pk[4];
    #pragma unroll
    for (int e = 0; e < 4; ++e){
      const int x = xh + j*8 + e*2;
      const float v0 = bv + sxin[x  ]*w0v + sxin[128+x  ]*w1v + sxin[256+x  ]*w2v;
      const float v1 = bv + sxin[x+1]*w0v + sxin[128+x+1]*w1v + sxin[256+x+1]*w2v;
      sht[(x  )*BPX + o] = f2bf(v0);
      sht[(x+1)*BPX + o] = f2bf(v1);
      const float h0 = v0*ss[x], h1 = v1*ss[x+1];
      xacc += h0*sm[x] + h1*sm[x+1];
      pk[e] = pk2(h0, h1);
    }
    q.x = pk[0]; q.y = pk[1]; q.z = pk[2]; q.w = pk[3];
    *(uint4*)&hs[((size_t)b*CC + o)*NN + x0 + xh + j*8] = q;
  }
  xacc += __shfl_xor(xacc, 1);
  if ((t & 1) == 0) atomicAdd(&x0out[b*CC + o], xacc);
  __syncthreads();
  // hT[x][c] coalesced
  for (int idx = t; idx < 128*16; idx += 256){
    const int x = idx >> 4, c8 = (idx & 15)*8;
    *(uint4*)&hT[((size_t)b*NN + x0 + x)*CC + c8] = *(const uint4*)&sht[x*BPX + c8];
  }
}

// ---------------------------------------------------------------- proj (MFMA): xc/xs partial sums
__global__ __launch_bounds__(256) void proj_kernel(
    const u16* __restrict__ hs, const u16* __restrict__ bc, const u16* __restrict__ bs,
    float* __restrict__ xc, float* __restrict__ xs)
{
  __shared__ u16 sha[128*APX];
  __shared__ u16 shc[64*APX];
  __shared__ u16 shs[64*APX];
  const int b  = blockIdx.x;
  const int kh = blockIdx.y;      // 0..1
  const int zc = blockIdx.z;      // 0..15 : x-chunk of 512
  const int t = threadIdx.x;
  const int w = t >> 6;
  const int l = t & 63;
  const int lm = l & 15, q = l >> 4;
  const f32x4 z4 = {0.f, 0.f, 0.f, 0.f};
  f32x4 accC[2][4], accS[2][4];
  #pragma unroll
  for (int mt = 0; mt < 2; ++mt)
    #pragma unroll
    for (int nt = 0; nt < 4; ++nt){ accC[mt][nt] = z4; accS[mt][nt] = z4; }

  const size_t hsbase = (size_t)b*CC*NN;
  const size_t bbase  = ((size_t)b*KK + kh*64)*NN;
  const int row = t >> 2, ch = (t & 3)*8;
  for (int st = 0; st < 16; ++st){
    const int x0 = zc*512 + st*32;
    __syncthreads();
    #pragma unroll
    for (int h = 0; h < 2; ++h){
      const int r = row + h*64;
      *(uint4*)&sha[r*APX + ch] = *(const uint4*)&hs[hsbase + (size_t)r*NN + x0 + ch];
    }
    *(uint4*)&shc[row*APX + ch] = *(const uint4*)&bc[bbase + (size_t)row*NN + x0 + ch];
    *(uint4*)&shs[row*APX + ch] = *(const uint4*)&bs[bbase + (size_t)row*NN + x0 + ch];
    __syncthreads();
    bf16x8 af[2];
    af[0] = *(const bf16x8*)&sha[(w*32      + lm)*APX + q*8];
    af[1] = *(const bf16x8*)&sha[(w*32 + 16 + lm)*APX + q*8];
    #pragma unroll
    for (int nt = 0; nt < 4; ++nt){
      const bf16x8 bfc = *(const bf16x8*)&shc[(nt*16 + lm)*APX + q*8];
      const bf16x8 bfs = *(const bf16x8*)&shs[(nt*16 + lm)*APX + q*8];
      #pragma unroll
      for (int mt = 0; mt < 2; ++mt){
        accC[mt][nt] = __builtin_amdgcn_mfma_f32_16x16x32_bf16(af[mt], bfc, accC[mt][nt], 0, 0, 0);
        accS[mt][nt] = __builtin_amdgcn_mfma_f32_16x16x32_bf16(af[mt], bfs, accS[mt][nt], 0, 0, 0);
      }
    }
  }
  #pragma unroll
  for (int mt = 0; mt < 2; ++mt){
    #pragma unroll
    for (int nt = 0; nt < 4; ++nt){
      const int k = kh*64 + nt*16 + lm;
      #pragma unroll
      for (int r = 0; r < 4; ++r){
        const int i = w*32 + mt*16 + q*4 + r;
        atomicAdd(&xc[((size_t)b*CC + i)*KK + k],  accC[mt][nt][r]);
        atomicAdd(&xs[((size_t)b*CC + i)*KK + k], -accS[mt][nt][r]);
      }
    }
  }
}

// ---------------------------------------------------------------- mix (fp32 in, bf16 out, folds +-2/N)
__global__ __launch_bounds__(256) void mix_kernel(
    const float* __restrict__ xc, const float* __restrict__ xs,
    const float* __restrict__ wcl, const float* __restrict__ wsl,
    u16* __restrict__ fcb, u16* __restrict__ fsb)
{
  const int b = blockIdx.x, og = blockIdx.y;
  const int t = threadIdx.x;
  const int k = t & 127, oh = t >> 7;
  const int o0 = og*8 + oh*4;
  float aC[4] = {0.f,0.f,0.f,0.f}, aS[4] = {0.f,0.f,0.f,0.f};
  const float* xcp = xc + (size_t)b*CC*KK + k;
  const float* xsp = xs + (size_t)b*CC*KK + k;
  const float* wcp = wcl + (size_t)o0*KK + k;
  const float* wsp = wsl + (size_t)o0*KK + k;
  for (int i = 0; i < CC; ++i){
    const float xcv = xcp[(size_t)i*KK];
    const float xsv = xsp[(size_t)i*KK];
    #pragma unroll
    for (int oo = 0; oo < 4; ++oo){
      const float a = wcp[((size_t)i*CC + oo)*KK];
      const float c = wsp[((size_t)i*CC + oo)*KK];
      aC[oo] += xcv*a - xsv*c;
      aS[oo] += xsv*a + xcv*c;
    }
  }
  const float sc = 2.0f/(float)NN;
  #pragma unroll
  for (int oo = 0; oo < 4; ++oo){
    fcb[((size_t)b*CC + o0+oo)*KK + k] = f2bf( aC[oo]*sc);
    fsb[((size_t)b*CC + o0+oo)*KK + k] = f2bf(-aS[oo]*sc);
  }
}

__global__ __launch_bounds__(128) void f0_kernel(
    const float* __restrict__ x0a, const float* __restrict__ w0l, float* __restrict__ f0b)
{
  const int b = blockIdx.x, o = threadIdx.x;
  float acc = 0.f;
  for (int i = 0; i < CC; ++i) acc += x0a[b*CC+i] * w0l[(size_t)i*CC + o];
  f0b[b*CC+o] = acc * (1.0f/(float)NN);
}

// ---------------------------------------------------------------- fused spectral + conv + gelu
// D[x][o] = sum_k bcT[x][k]*fcb[o][k] + sum_k bsT[x][k]*fsb[o][k] + sum_i hT[x][i]*cwb[o][i]
//           + f0[o]*m[x] + cb[o] ; act? gelu ; write hT in-place + hs (scaled) + x0next
__global__ __launch_bounds__(256) void fused_kernel(
    const u16* __restrict__ bcT, const u16* __restrict__ bsT,
    u16* __restrict__ hT,
    const u16* __restrict__ fcb, const u16* __restrict__ fsb,
    const u16* __restrict__ cwb, const float* __restrict__ cb,
    const float* __restrict__ f0b, const float* __restrict__ mA, const float* __restrict__ sA,
    u16* __restrict__ hsout, float* __restrict__ x0next, const int act)
{
  __shared__ u16 smem[128*BPX];     // staging (2x 128*APX) then [o][x] transpose buffer
  __shared__ float sm[128], ssc[128], sf0[128], scb[128];
  u16* sa = smem;
  u16* sbt = smem + 128*APX;
  const int b  = blockIdx.x;
  const int x0 = blockIdx.y*128;
  const int t = threadIdx.x;
  const int w = t >> 6, l = t & 63, lm = l & 15, q = l >> 4;
  if (t < 128){
    sm[t]  = mA[b*NN + x0 + t];
    ssc[t] = sA[b*NN + x0 + t];
    sf0[t] = f0b[b*CC + t];
    scb[t] = cb[t];
  }
  const f32x4 z4 = {0.f,0.f,0.f,0.f};
  f32x4 acc[2][8];
  #pragma unroll
  for (int mt = 0; mt < 2; ++mt)
    #pragma unroll
    for (int nt = 0; nt < 8; ++nt) acc[mt][nt] = z4;

  const u16* Ap0 = bcT + ((size_t)b*NN + x0)*KK;
  const u16* Ap1 = bsT + ((size_t)b*NN + x0)*KK;
  const u16* Ap2 = hT  + ((size_t)b*NN + x0)*CC;
  const u16* Bp0 = fcb + (size_t)b*CC*KK;
  const u16* Bp1 = fsb + (size_t)b*CC*KK;
  const u16* Bp2 = cwb;
  const int row = t >> 2, ch = (t & 3)*8;
  for (int s = 0; s < 12; ++s){
    const int g = s >> 2, kk = (s & 3)*32;
    const u16* Ap = (g == 0) ? Ap0 : (g == 1) ? Ap1 : Ap2;
    const u16* Bp = (g == 0) ? Bp0 : (g == 1) ? Bp1 : Bp2;
    __syncthreads();
    #pragma unroll
    for (int h = 0; h < 2; ++h){
      const int r = row + h*64;
      *(uint4*)&sa [r*APX + ch] = *(const uint4*)&Ap[(size_t)r*KK + kk + ch];
      *(uint4*)&sbt[r*APX + ch] = *(const uint4*)&Bp[(size_t)r*KK + kk + ch];
    }
    __syncthreads();
    bf16x8 af[2];
    af[0] = *(const bf16x8*)&sa[(w*32      + lm)*APX + q*8];
    af[1] = *(const bf16x8*)&sa[(w*32 + 16 + lm)*APX + q*8];
    #pragma unroll
    for (int nt = 0; nt < 8; ++nt){
      const bf16x8 bf = *(const bf16x8*)&sbt[(nt*16 + lm)*APX + q*8];
      acc[0][nt] = __builtin_amdgcn_mfma_f32_16x16x32_bf16(af[0], bf, acc[0][nt], 0, 0, 0);
      acc[1][nt] = __builtin_amdgcn_mfma_f32_16x16x32_bf16(af[1], bf, acc[1][nt], 0, 0, 0);
    }
  }
  __syncthreads();
  // finish values, stash into smem as [o][x] (stride BPX)
  #pragma unroll
  for (int mt = 0; mt < 2; ++mt){
    const int xb = w*32 + mt*16 + q*4;
    #pragma unroll
    for (int nt = 0; nt < 8; ++nt){
      const int o = nt*16 + lm;
      const float f0v = sf0[o], cbv = scb[o];
      ushort4 pk4;
      float v0 = acc[mt][nt][0] + f0v*sm[xb+0] + cbv;
      float v1 = acc[mt][nt][1] + f0v*sm[xb+1] + cbv;
      float v2 = acc[mt][nt][2] + f0v*sm[xb+2] + cbv;
      float v3 = acc[mt][nt][3] + f0v*sm[xb+3] + cbv;
      if (act){ v0 = gelu_f(v0); v1 = gelu_f(v1); v2 = gelu_f(v2); v3 = gelu_f(v3); }
      pk4.x = f2bf(v0); pk4.y = f2bf(v1); pk4.z = f2bf(v2); pk4.w = f2bf(v3);
      *(ushort4*)&smem[o*BPX + xb] = pk4;
    }
  }
  __syncthreads();
  // pass A: hs (scaled) + x0 partial
  if (hsout){
    const int o = t >> 1, xh = (t & 1)*64;
    float xacc = 0.f;
    #pragma unroll 2
    for (int j = 0; j < 8; ++j){
      const int xb2 = xh + j*8;
      const uint4 rv = *(const uint4*)&smem[o*BPX + xb2];
      float h0 = bf2f((u16)(rv.x & 0xffff)) * ssc[xb2+0];
      float h1 = bf2f((u16)(rv.x >> 16))    * ssc[xb2+1];
      float h2 = bf2f((u16)(rv.y & 0xffff)) * ssc[xb2+2];
      float h3 = bf2f((u16)(rv.y >> 16))    * ssc[xb2+3];
      float h4 = bf2f((u16)(rv.z & 0xffff)) * ssc[xb2+4];
      float h5 = bf2f((u16)(rv.z >> 16))    * ssc[xb2+5];
      float h6 = bf2f((u16)(rv.w & 0xffff)) * ssc[xb2+6];
      float h7 = bf2f((u16)(rv.w >> 16))    * ssc[xb2+7];
      xacc += h0*sm[xb2+0] + h1*sm[xb2+1] + h2*sm[xb2+2] + h3*sm[xb2+3]
            + h4*sm[xb2+4] + h5*sm[xb2+5] + h6*sm[xb2+6] + h7*sm[xb2+7];
      uint4 qv;
      qv.x = pk2(h0, h1); qv.y = pk2(h2, h3); qv.z = pk2(h4, h5); qv.w = pk2(h6, h7);
      *(uint4*)&hsout[((size_t)b*CC + o)*NN + x0 + xb2] = qv;
    }
    xacc += __shfl_xor(xacc, 1);
    if ((t & 1) == 0 && x0next) atomicAdd(&x0next[b*CC + o], xacc);
  }
  // pass B: hT[x][o] (in-place safe: block owns its x-rows)
  {
    const int x = t >> 1, oh = (t & 1)*64;
    #pragma unroll 2
    for (int j = 0; j < 8; ++j){
      const int ob = oh + j*8;
      uint4 qv;
      qv.x = (u32)smem[(ob+0)*BPX + x] | ((u32)smem[(ob+1)*BPX + x] << 16);
      qv.y = (u32)smem[(ob+2)*BPX + x] | ((u32)smem[(ob+3)*BPX + x] << 16);
      qv.z = (u32)smem[(ob+4)*BPX + x] | ((u32)smem[(ob+5)*BPX + x] << 16);
      qv.w = (u32)smem[(ob+6)*BPX + x] | ((u32)smem[(ob+7)*BPX + x] << 16);
      *(uint4*)&hT[((size_t)b*NN + x0 + x)*CC + ob] = qv;
    }
  }
}

// ---------------------------------------------------------------- final MLP (MFMA)
__global__ __launch_bounds__(256) void final_kernel(
    const u16* __restrict__ hT, const u16* __restrict__ w1T,
    const float* __restrict__ b1, const float* __restrict__ w2, const float* __restrict__ b2,
    float* __restrict__ out)
{
  __shared__ u16 sa[128*APX];
  __shared__ u16 sbt[128*APX];
  __shared__ float sb1[128], sw2[128];
  const int b  = blockIdx.x;
  const int x0 = blockIdx.y*128;
  const int t = threadIdx.x;
  const int w = t >> 6, l = t & 63, lm = l & 15, q = l >> 4;
  if (t < 128){ sb1[t] = b1[t]; sw2[t] = w2[t]; }
  const float b2v = b2[0];
  const f32x4 z4 = {0.f,0.f,0.f,0.f};
  f32x4 acc[2][8];
  #pragma unroll
  for (int mt = 0; mt < 2; ++mt)
    #pragma unroll
    for (int nt = 0; nt < 8; ++nt) acc[mt][nt] = z4;
  const u16* Ap = hT + ((size_t)b*NN + x0)*CC;
  const int row = t >> 2, ch = (t & 3)*8;
  for (int s = 0; s < 4; ++s){
    const int kk = s*32;
    __syncthreads();
    #pragma unroll
    for (int h = 0; h < 2; ++h){
      const int r = row + h*64;
      *(uint4*)&sa [r*APX + ch] = *(const uint4*)&Ap [(size_t)r*CC + kk + ch];
      *(uint4*)&sbt[r*APX + ch] = *(const uint4*)&w1T[(size_t)r*CC + kk + ch];
    }
    __syncthreads();
    bf16x8 af[2];
    af[0] = *(const bf16x8*)&sa[(w*32      + lm)*APX + q*8];
    af[1] = *(const bf16x8*)&sa[(w*32 + 16 + lm)*APX + q*8];
    #pragma unroll
    for (int nt = 0; nt < 8; ++nt){
      const bf16x8 bf = *(const bf16x8*)&sbt[(nt*16 + lm)*APX + q*8];
      acc[0][nt] = __builtin_amdgcn_mfma_f32_16x16x32_bf16(af[0], bf, acc[0][nt], 0, 0, 0);
      acc[1][nt] = __builtin_amdgcn_mfma_f32_16x16x32_bf16(af[1], bf, acc[1][nt], 0, 0, 0);
    }
  }
  #pragma unroll
  for (int mt = 0; mt < 2; ++mt){
    #pragma unroll
    for (int r = 0; r < 4; ++r){
      float s = 0.f;
      #pragma unroll
      for (int nt = 0; nt < 8; ++nt){
        const int f = nt*16 + lm;
        s += gelu_f(acc[mt][nt][r] + sb1[f]) * sw2[f];
      }
      s += __shfl_xor(s, 1);
      s += __shfl_xor(s, 2);
      s += __shfl_xor(s, 4);
      s += __shfl_xor(s, 8);
      if (lm == 0){
        const int x = x0 + w*32 + mt*16 + q*4 + r;
        out[(size_t)b*NN + x] = s + b2v;
      }
    }
  }
}

// ---------------------------------------------------------------- host
extern "C" void kernel_launch(void* const* d_in, const int* in_sizes, int n_in,
                              void* d_out, int out_size, void* d_ws, size_t ws_size,
                              hipStream_t stream)
{
  const float* X     = (const float*)d_in[0];
  const float* modes = (const float*)d_in[1];
  const float* fc0w  = (const float*)d_in[2];
  const float* fc0b  = (const float*)d_in[3];
  const float* wc    = (const float*)d_in[4];
  const float* wsm   = (const float*)d_in[5];
  const float* w0    = (const float*)d_in[6];
  const float* convw = (const float*)d_in[7];
  const float* convb = (const float*)d_in[8];
  const float* fc1w  = (const float*)d_in[9];
  const float* fc1b  = (const float*)d_in[10];
  const float* fc2w  = (const float*)d_in[11];
  const float* fc2b  = (const float*)d_in[12];
  float* out = (float*)d_out;

  const size_t nBKN = (size_t)BB*KK*NN;   // 16.78M
  const size_t nBCK = (size_t)BB*CC*KK;   // 262144
  const size_t nBC  = (size_t)BB*CC;      // 2048
  const size_t nBN  = (size_t)BB*NN;      // 131072

  char* p = (char*)d_ws;
  u16* bc  = (u16*)p; p += nBKN*2;
  u16* bs  = (u16*)p; p += nBKN*2;
  u16* bcT = (u16*)p; p += nBKN*2;
  u16* bsT = (u16*)p; p += nBKN*2;
  u16* hs  = (u16*)p; p += nBKN*2;
  u16* hT  = (u16*)p; p += nBKN*2;
  float* xcA = (float*)p; p += nBCK*4;
  float* xsA = (float*)p; p += nBCK*4;
  float* x0A = (float*)p; p += 4*nBC*4;   // per-layer x0 buffers
  u16* fcb = (u16*)p; p += nBCK*2;
  u16* fsb = (u16*)p; p += nBCK*2;
  float* f0b = (float*)p; p += nBC*4;
  float* mA  = (float*)p; p += nBN*4;
  float* sA  = (float*)p; p += nBN*4;
  u16* cwb = (u16*)p; p += (size_t)LL*CC*CC*2;
  u16* w1T = (u16*)p; p += (size_t)CC*CC*2;

  // zero atomic-accumulation region (xc, xs, x0[0..3]) — contiguous
  hipMemsetAsync(xcA, 0, (2*nBCK + 4*nBC)*sizeof(float), stream);

  cvt_kernel<<<1, 256, 0, stream>>>(convw, fc1w, cwb, w1T);
  bases_kernel<<<dim3(BB, NN/64), 256, 0, stream>>>(X, modes, bc, bs, bcT, bsT, mA, sA);
  fc0_kernel<<<dim3(BB, NN/128), 256, 0, stream>>>(X, fc0w, fc0b, mA, sA, hs, hT, x0A);

  for (int l = 0; l < LL; ++l){
    proj_kernel<<<dim3(BB, 2, 16), 256, 0, stream>>>(hs, bc, bs, xcA, xsA);
    mix_kernel<<<dim3(BB, 16), 256, 0, stream>>>(xcA, xsA,
        wc + (size_t)l*CC*CC*KK, wsm + (size_t)l*CC*CC*KK, fcb, fsb);
    f0_kernel<<<dim3(BB), 128, 0, stream>>>(x0A + (size_t)l*nBC, w0 + (size_t)l*CC*CC, f0b);
    if (l < LL-1)
      hipMemsetAsync(xcA, 0, 2*nBCK*sizeof(float), stream);  // re-zero for next layer's proj
    fused_kernel<<<dim3(BB, NN/128), 256, 0, stream>>>(
        bcT, bsT, hT, fcb, fsb,
        cwb + (size_t)l*CC*CC, convb + (size_t)l*CC,
        f0b, mA, sA,
        (l < LL-1) ? hs : (u16*)nullptr,
        (l < LL-1) ? (x0A + (size_t)(l+1)*nBC) : (float*)nullptr,
        (l < LL-1) ? 1 : 0);
  }
  final_kernel<<<dim3(BB, NN/128), 256, 0, stream>>>(hT, w1T, fc1b, fc2w, fc2b, out);
}